// Round 12
// baseline (92.071 us; speedup 1.0000x reference)
//
#include <hip/hip_runtime.h>

// VQ-VAE quantization via fused bf16-MFMA argmin. 1024 blocks x 128 rows,
// per-subtile software pipeline: GATHER(s-1) | COMPUTE(s) | STORE(s-1) |
// PACK(s+1), lgkm-only barriers, swizzled LDS, fused last-block loss.
// B=32, D=64, HW=4096, K=512.
// out[0..8388608)=quantized NCHW, out[8388608]=loss=1.25*mean((q-x)^2).
#define KK    512
#define DD    64
#define HWSZ  4096
#define NROWS 131072
#define RPB   128
#define NSUB  4
#define NBLK  (NROWS / RPB)        // 1024

typedef short short8 __attribute__((ext_vector_type(8)));
typedef float f32x16 __attribute__((ext_vector_type(16)));

static __device__ __forceinline__ unsigned cvtpk(float lo, float hi) {
    unsigned r;                    // r = bf16(lo) | bf16(hi)<<16, RNE
    asm("v_cvt_pk_bf16_f32 %0, %1, %2" : "=v"(r) : "v"(lo), "v"(hi));
    return r;
}
static __device__ __forceinline__ float    u2f(unsigned u) { return __builtin_bit_cast(float, u); }
static __device__ __forceinline__ unsigned f2u(float f)    { return __builtin_bit_cast(unsigned, f); }
static __device__ __forceinline__ float mx3(float a, float b, float c) {
    return fmaxf(fmaxf(a, b), c);  // clang fuses to v_max3_f32
}

// lgkm-only barrier: global loads stay in flight (no vmcnt drain)
#define LGKM0_BAR() do { asm volatile("s_waitcnt lgkmcnt(0)" ::: "memory"); \
                         __builtin_amdgcn_s_barrier();                      \
                         asm volatile("" ::: "memory"); } while (0)

__global__ __launch_bounds__(256, 2) void vq_mfma(
    const float* __restrict__ x, const float* __restrict__ emb,
    float* __restrict__ out, unsigned* __restrict__ counter,
    float* __restrict__ partial)
{
    __shared__ float    sH[KK];            // ||e_k||^2 (for loss)
    __shared__ unsigned sX[2][32 * 32];    // 8 KB double-buffered packed bf16 x
    __shared__ float    sKey[NSUB][4][33]; // [subtile][wave][row+pad] keys
    __shared__ float    sRed[4];
    __shared__ int      sLast;

    const int tid  = threadIdx.x;
    const int lane = tid & 63;
    const int w    = tid >> 6;             // wave owns codes [w*128, w*128+128)
    const int g    = lane >> 5;
    const int col  = lane & 31;
    const int wbase = w * 128;

    const int base = blockIdx.x * RPB;     // 128 consecutive hw rows, b constant
    const int b    = base >> 12;
    const int hwb  = base & 4095;
    const float* xblk = x   + (size_t)b * (DD * HWSZ) + hwb;
    float*       oblk = out + (size_t)b * (DD * HWSZ) + hwb;

    const int cp  = tid >> 3;              // staging: channel pair 0..31
    const int hwq = (tid & 7) * 4;         // staging: hw quad
    const int swq = hwq ^ ((cp & 7) << 2); // swizzled write slot (bank-free)
    const int eq_  = tid & 7;              // epilogue: row quad
    const int ecg_ = tid >> 3;             // epilogue: channel pair 0..31

#define LOAD(PA, PB, S) do { const float* xs = xblk + 32 * (S);               \
        PA = *(const float4*)(xs + (size_t)(2*cp)   * HWSZ + hwq);            \
        PB = *(const float4*)(xs + (size_t)(2*cp+1) * HWSZ + hwq); } while (0)

    // ---- 2-deep rolling prefetch ----
    float4 Pa0, Pb0, Pa1, Pb1;
    LOAD(Pa0, Pb0, 0);
    LOAD(Pa1, Pb1, 1);

    // ---- persistent codebook A-fragments; ||e||^2 -> sH (loss only) ----
    short8 afrag[4][4];
    #pragma unroll
    for (int ct = 0; ct < 4; ++ct) {
        const int code = wbase + ct * 32 + col;
        float e2h = 0.f;
        #pragma unroll
        for (int m = 0; m < 4; ++m) {
            const float* ep = emb + code * DD + m * 16 + 8 * g;
            float4 a  = *(const float4*)ep;
            float4 b4 = *(const float4*)(ep + 4);
            union { unsigned u[4]; short8 s; } cv;
            cv.u[0] = cvtpk(a.x, a.y);   cv.u[1] = cvtpk(a.z, a.w);
            cv.u[2] = cvtpk(b4.x, b4.y); cv.u[3] = cvtpk(b4.z, b4.w);
            afrag[ct][m] = cv.s;
            e2h = fmaf(a.x,a.x,e2h);   e2h = fmaf(a.y,a.y,e2h);
            e2h = fmaf(a.z,a.z,e2h);   e2h = fmaf(a.w,a.w,e2h);
            e2h = fmaf(b4.x,b4.x,e2h); e2h = fmaf(b4.y,b4.y,e2h);
            e2h = fmaf(b4.z,b4.z,e2h); e2h = fmaf(b4.w,b4.w,e2h);
        }
        float e2f = e2h + __shfl_xor(e2h, 32, 64);
        if (lane < 32) sH[code] = e2f;
    }

    float lsum = 0.f;                      // x^2 terms + per-row loss terms

#define PACK(BUF, FA, FB)                                                     \
    do {                                                                      \
        uint4 dw = { cvtpk(FA.x, FB.x), cvtpk(FA.y, FB.y),                    \
                     cvtpk(FA.z, FB.z), cvtpk(FA.w, FB.w) };                  \
        *(uint4*)&sX[BUF][cp * 32 + swq] = dw;                                \
        lsum = fmaf(FA.x,FA.x,lsum); lsum = fmaf(FA.y,FA.y,lsum);             \
        lsum = fmaf(FA.z,FA.z,lsum); lsum = fmaf(FA.w,FA.w,lsum);             \
        lsum = fmaf(FB.x,FB.x,lsum); lsum = fmaf(FB.y,FB.y,lsum);             \
        lsum = fmaf(FB.z,FB.z,lsum); lsum = fmaf(FB.w,FB.w,lsum);             \
    } while (0)

    const unsigned cbase = (unsigned)(wbase + 4 * g);
    int colx[4];                           // swizzled read columns
    #pragma unroll
    for (int j = 0; j < 4; ++j) colx[j] = col ^ ((4 * g + j) << 2);

#define COMPUTE(S, BUF)                                                       \
    do {                                                                      \
        short8 bfrag[4];                                                      \
        _Pragma("unroll")                                                     \
        for (int m = 0; m < 4; ++m) {                                         \
            union { unsigned u[4]; short8 s8; } cv;                           \
            _Pragma("unroll")                                                 \
            for (int j = 0; j < 4; ++j)                                       \
                cv.u[j] = sX[BUF][(m * 8 + 4 * g + j) * 32 + colx[j]];        \
            bfrag[m] = cv.s8;                                                 \
        }                                                                     \
        float kwave;                                                          \
        _Pragma("unroll")                                                     \
        for (int ct = 0; ct < 4; ++ct) {                                      \
            f32x16 acc = {};                                                  \
            _Pragma("unroll")                                                 \
            for (int m = 0; m < 4; ++m)                                       \
                acc = __builtin_amdgcn_mfma_f32_32x32x16_bf16(                \
                          afrag[ct][m], bfrag[m], acc, 0, 0, 0);              \
            float k[16];                                                      \
            _Pragma("unroll")                                                 \
            for (int r = 0; r < 16; ++r)                                      \
                k[r] = u2f((f2u(acc[r]) & 0xFFFFFE00u) |                      \
                           (cbase + (unsigned)(ct * 32 + (r & 3) + 8 * (r >> 2)))); \
            float t0 = mx3(k[0],  k[1],  k[2]);                               \
            float t1 = mx3(k[3],  k[4],  k[5]);                               \
            float t2 = mx3(k[6],  k[7],  k[8]);                               \
            float t3 = mx3(k[9],  k[10], k[11]);                              \
            float t4 = mx3(k[12], k[13], k[14]);                              \
            float kct = mx3(mx3(t0, t1, k[15]), fmaxf(t2, t3), t4);           \
            kwave = ct ? fmaxf(kwave, kct) : kct;                             \
        }                                                                     \
        float k2 = fmaxf(kwave, __shfl_xor(kwave, 32, 64));                   \
        if (lane < 32) sKey[S][w][lane] = k2;                                 \
    } while (0)

    float2 gv[4];                          // gathered (2 channels) per row quad

#define GATHER(S)                                                             \
    do {                                                                      \
        _Pragma("unroll")                                                     \
        for (int j = 0; j < 4; ++j) {                                         \
            const int r32 = 4 * eq_ + j;                                      \
            float kf = fmaxf(fmaxf(sKey[S][0][r32], sKey[S][1][r32]),         \
                             fmaxf(sKey[S][2][r32], sKey[S][3][r32]));        \
            const unsigned ku = f2u(kf);                                      \
            const int code = (int)(ku & 511u);                                \
            if (ecg_ == 0)                                                    \
                lsum += fmaf(-2.f, u2f(ku & 0xFFFFFE00u), sH[code]);          \
            gv[j] = *(const float2*)(emb + code * DD + 2 * ecg_);             \
        }                                                                     \
    } while (0)

#define STORE(S)                                                              \
    do {                                                                      \
        float* ob = oblk + 32 * (S) + 4 * eq_;                                \
        *(float4*)(ob + (size_t)(2*ecg_)   * HWSZ) =                          \
            make_float4(gv[0].x, gv[1].x, gv[2].x, gv[3].x);                  \
        *(float4*)(ob + (size_t)(2*ecg_+1) * HWSZ) =                          \
            make_float4(gv[0].y, gv[1].y, gv[2].y, gv[3].y);                  \
    } while (0)

    // ---- software-pipelined phases ----
    PACK(0, Pa0, Pb0);
    LOAD(Pa0, Pb0, 2);
    LGKM0_BAR();                           // #1: sX0 + sH ready

    COMPUTE(0, 0);
    PACK(1, Pa1, Pb1);
    LOAD(Pa1, Pb1, 3);
    LGKM0_BAR();                           // #2: sKey0, sX1 ready

    GATHER(0);                             // emb loads fly under COMPUTE(1)
    COMPUTE(1, 1);
    PACK(2, Pa0, Pb0);
    STORE(0);
    LGKM0_BAR();                           // #3: sKey1, sX0(new) ready

    GATHER(1);
    COMPUTE(2, 0);
    PACK(3, Pa1, Pb1);
    STORE(1);
    LGKM0_BAR();                           // #4: sKey2, sX1(new) ready

    GATHER(2);
    COMPUTE(3, 1);
    STORE(2);
    LGKM0_BAR();                           // #5: sKey3 ready

    GATHER(3);
    STORE(3);

#undef LOAD
#undef PACK
#undef COMPUTE
#undef GATHER
#undef STORE

    // ---- block loss reduction + fused last-block finalization ----
    #pragma unroll
    for (int off = 32; off; off >>= 1) lsum += __shfl_down(lsum, off, 64);
    if (lane == 0) sRed[w] = lsum;
    __syncthreads();
    if (tid == 0) {
        float total = (sRed[0] + sRed[1]) + (sRed[2] + sRed[3]);
        __hip_atomic_store(&partial[blockIdx.x], total,
                           __ATOMIC_RELEASE, __HIP_MEMORY_SCOPE_AGENT);
        unsigned prev = __hip_atomic_fetch_add(counter, 1u,
                           __ATOMIC_ACQ_REL, __HIP_MEMORY_SCOPE_AGENT);
        sLast = (prev == NBLK - 1) ? 1 : 0;
    }
    __syncthreads();
    if (sLast) {                           // exactly one block runs this
        float v = 0.f;
        #pragma unroll
        for (int i = 0; i < NBLK / 256; ++i)   // fixed order: deterministic
            v += __hip_atomic_load(&partial[tid + 256 * i],
                                   __ATOMIC_RELAXED, __HIP_MEMORY_SCOPE_AGENT);
        #pragma unroll
        for (int off = 32; off; off >>= 1) v += __shfl_down(v, off, 64);
        if (lane == 0) sRed[w] = v;
        __syncthreads();
        if (tid == 0)
            out[(size_t)NROWS * DD] =
                ((sRed[0] + sRed[1]) + (sRed[2] + sRed[3])) * (1.25f / 8388608.0f);
    }
}

extern "C" void kernel_launch(void* const* d_in, const int* in_sizes, int n_in,
                              void* d_out, int out_size, void* d_ws, size_t ws_size,
                              hipStream_t stream) {
    const float* x   = (const float*)d_in[0];   // [32,64,64,64] NCHW
    const float* emb = (const float*)d_in[1];   // [512,64]
    float* out        = (float*)d_out;
    unsigned* counter = (unsigned*)d_ws;        // zeroed every launch below
    float* partial    = (float*)((char*)d_ws + 256);   // NBLK floats

    hipMemsetAsync(d_ws, 0, 256, stream);
    vq_mfma<<<NBLK, 256, 0, stream>>>(x, emb, out, counter, partial);
}

// Round 14
// 62.580 us; speedup vs baseline: 1.4712x; 1.4712x over previous
//
#include <hip/hip_runtime.h>

// VQ-VAE quantization via fused bf16-MFMA argmin. 512 blocks x 256 threads,
// whole 256-row tile staged at once, ONE barrier before compute, one before
// epilogue, fused last-block loss finalization (counter memset each launch).
// B=32, D=64, HW=4096, K=512.
// out[0..8388608)=quantized NCHW, out[8388608]=loss=1.25*mean((q-x)^2).
#define KK    512
#define DD    64
#define HWSZ  4096
#define NROWS 131072
#define RPB   256                  // rows per block
#define NSUB  8                    // 32-row sub-tiles per block
#define NBLK  (NROWS / RPB)        // 512

typedef short short8 __attribute__((ext_vector_type(8)));
typedef float f32x16 __attribute__((ext_vector_type(16)));

static __device__ __forceinline__ unsigned cvtpk(float lo, float hi) {
    unsigned r;                    // r = bf16(lo) | bf16(hi)<<16, RNE
    asm("v_cvt_pk_bf16_f32 %0, %1, %2" : "=v"(r) : "v"(lo), "v"(hi));
    return r;
}
static __device__ __forceinline__ float    u2f(unsigned u) { return __builtin_bit_cast(float, u); }
static __device__ __forceinline__ unsigned f2u(float f)    { return __builtin_bit_cast(unsigned, f); }
static __device__ __forceinline__ float mx3(float a, float b, float c) {
    return fmaxf(fmaxf(a, b), c);  // clang fuses to v_max3_f32
}

// lgkm-only barrier: global loads stay in flight (no vmcnt drain)
#define LGKM0_BAR() do { asm volatile("s_waitcnt lgkmcnt(0)" ::: "memory"); \
                         __builtin_amdgcn_s_barrier();                      \
                         asm volatile("" ::: "memory"); } while (0)

__global__ __launch_bounds__(256, 2) void vq_mfma(
    const float* __restrict__ x, const float* __restrict__ emb,
    float* __restrict__ out, unsigned* __restrict__ counter,
    float* __restrict__ partial)
{
    __shared__ float    sH[KK];             // -0.5*||e_k||^2 (wave-private slices)
    __shared__ unsigned sX[NSUB][32 * 32];  // 32 KB: whole 256-row tile, packed bf16
    __shared__ float    sKey[NSUB][4][32];  // [subtile][wave][row] packed keys
    __shared__ float    sRed[4];
    __shared__ int      sLast;

    const int tid  = threadIdx.x;
    const int lane = tid & 63;
    const int w    = tid >> 6;              // wave owns codes [w*128, w*128+128)
    const int g    = lane >> 5;
    const int wbase = w * 128;

    const int base = blockIdx.x * RPB;      // 256 consecutive hw rows, b constant
    const int b    = base >> 12;
    const int hwb  = base & 4095;
    const float* xblk = x   + (size_t)b * (DD * HWSZ) + hwb;
    float*       oblk = out + (size_t)b * (DD * HWSZ) + hwb;

    const int cp  = tid >> 3;               // staging: channel pair 0..31
    const int hwq = (tid & 7) * 4;          // staging: hw quad

    // ---- issue ALL x loads up front; latency hidden under A-frag setup ----
    float4 xa[NSUB], xbv[NSUB];
    #pragma unroll
    for (int s = 0; s < NSUB; ++s) {
        const float* xs = xblk + 32 * s;
        xa[s]  = *(const float4*)(xs + (size_t)(2*cp)   * HWSZ + hwq);
        xbv[s] = *(const float4*)(xs + (size_t)(2*cp+1) * HWSZ + hwq);
    }

    // ---- persistent codebook A-fragments; -e^2/2 (wave-private, no barrier) ----
    short8 afrag[4][4];
    #pragma unroll
    for (int ct = 0; ct < 4; ++ct) {
        const int code = wbase + ct * 32 + (lane & 31);
        float e2h = 0.f;
        #pragma unroll
        for (int m = 0; m < 4; ++m) {
            const float* ep = emb + code * DD + m * 16 + 8 * g;
            float4 a  = *(const float4*)ep;
            float4 b4 = *(const float4*)(ep + 4);
            union { unsigned u[4]; short8 s; } cv;
            cv.u[0] = cvtpk(a.x, a.y);   cv.u[1] = cvtpk(a.z, a.w);
            cv.u[2] = cvtpk(b4.x, b4.y); cv.u[3] = cvtpk(b4.z, b4.w);
            afrag[ct][m] = cv.s;
            e2h = fmaf(a.x,a.x,e2h);   e2h = fmaf(a.y,a.y,e2h);
            e2h = fmaf(a.z,a.z,e2h);   e2h = fmaf(a.w,a.w,e2h);
            e2h = fmaf(b4.x,b4.x,e2h); e2h = fmaf(b4.y,b4.y,e2h);
            e2h = fmaf(b4.z,b4.z,e2h); e2h = fmaf(b4.w,b4.w,e2h);
        }
        float e2f = e2h + __shfl_xor(e2h, 32, 64);
        if (lane < 32) sH[code] = -0.5f * e2f;
    }

    // ---- pack whole tile -> sX; thread-local fp32 sum(x^2) ----
    float xsq = 0.f;
    #pragma unroll
    for (int s = 0; s < NSUB; ++s) {
        float4 fa = xa[s], fb = xbv[s];
        uint4 dw = { cvtpk(fa.x, fb.x), cvtpk(fa.y, fb.y),
                     cvtpk(fa.z, fb.z), cvtpk(fa.w, fb.w) };
        *(uint4*)&sX[s][cp * 32 + hwq] = dw;
        xsq = fmaf(fa.x,fa.x,xsq); xsq = fmaf(fa.y,fa.y,xsq);
        xsq = fmaf(fa.z,fa.z,xsq); xsq = fmaf(fa.w,fa.w,xsq);
        xsq = fmaf(fb.x,fb.x,xsq); xsq = fmaf(fb.y,fb.y,xsq);
        xsq = fmaf(fb.z,fb.z,xsq); xsq = fmaf(fb.w,fb.w,xsq);
    }

    // ---- hoist acc-init to registers (wave-own sH slice, read once) ----
    float4 e2r[4][4];
    #pragma unroll
    for (int ct = 0; ct < 4; ++ct)
        #pragma unroll
        for (int i = 0; i < 4; ++i)
            e2r[ct][i] = *(const float4*)(sH + wbase + ct * 32 + 4 * g + 8 * i);

    LGKM0_BAR();                            // #1: all sX staged (sH wave-private)

    const unsigned cbase = (unsigned)(wbase + 4 * g);

    // ---- 8 sub-tiles back-to-back, ZERO barriers between ----
    #pragma unroll 1
    for (int s = 0; s < NSUB; ++s) {
        short8 bfrag[4];
        #pragma unroll
        for (int m = 0; m < 4; ++m) {
            const unsigned* sp = &sX[s][(m * 8 + 4 * g) * 32 + (lane & 31)];
            union { unsigned u[4]; short8 s8; } cv;
            cv.u[0] = sp[0]; cv.u[1] = sp[32]; cv.u[2] = sp[64]; cv.u[3] = sp[96];
            bfrag[m] = cv.s8;
        }
        float kwave;
        #pragma unroll
        for (int ct = 0; ct < 4; ++ct) {
            f32x16 acc;
            #pragma unroll
            for (int i = 0; i < 4; ++i) {
                acc[4*i]   = e2r[ct][i].x; acc[4*i+1] = e2r[ct][i].y;
                acc[4*i+2] = e2r[ct][i].z; acc[4*i+3] = e2r[ct][i].w;
            }
            #pragma unroll
            for (int m = 0; m < 4; ++m)
                acc = __builtin_amdgcn_mfma_f32_32x32x16_bf16(afrag[ct][m], bfrag[m], acc, 0, 0, 0);
            float k[16];
            #pragma unroll
            for (int r = 0; r < 16; ++r)
                k[r] = u2f((f2u(acc[r]) & 0xFFFFFE00u) |
                           (cbase + (unsigned)(ct * 32 + (r & 3) + 8 * (r >> 2))));
            float t0 = mx3(k[0],  k[1],  k[2]);
            float t1 = mx3(k[3],  k[4],  k[5]);
            float t2 = mx3(k[6],  k[7],  k[8]);
            float t3 = mx3(k[9],  k[10], k[11]);
            float t4 = mx3(k[12], k[13], k[14]);
            float kct = mx3(mx3(t0, t1, k[15]), fmaxf(t2, t3), t4);
            kwave = ct ? fmaxf(kwave, kct) : kct;
        }
        float k2 = fmaxf(kwave, __shfl_xor(kwave, 32, 64));
        if (lane < 32) sKey[s][w][lane] = k2;
    }

    LGKM0_BAR();                            // #2: all sKey slices ready

    // ---- mega-epilogue: thread = (quad 0..63, 16-channel group 0..3) ----
    const int quad = tid & 63;              // rows 4*quad .. 4*quad+3
    const int cgrp = tid >> 6;              // channels 16*cgrp .. 16*cgrp+15
    const int s    = quad >> 3;             // sub-tile of this quad
    float lsum = xsq;                       // loss: sum x^2 - 2*sum(best score)
    float gq[4][16];
    #pragma unroll
    for (int j = 0; j < 4; ++j) {
        const int r32 = (quad & 7) * 4 + j;
        float kf = fmaxf(fmaxf(sKey[s][0][r32], sKey[s][1][r32]),
                         fmaxf(sKey[s][2][r32], sKey[s][3][r32]));
        const int code = (int)(f2u(kf) & 511u);
        if (cgrp == 0)
            lsum = fmaf(-2.f, u2f(f2u(kf) & 0xFFFFFE00u), lsum);
        const float* eq = emb + code * DD + 16 * cgrp;
        float4 e0 = *(const float4*)eq;
        float4 e1 = *(const float4*)(eq + 4);
        float4 e2 = *(const float4*)(eq + 8);
        float4 e3 = *(const float4*)(eq + 12);
        gq[j][ 0] = e0.x; gq[j][ 1] = e0.y; gq[j][ 2] = e0.z; gq[j][ 3] = e0.w;
        gq[j][ 4] = e1.x; gq[j][ 5] = e1.y; gq[j][ 6] = e1.z; gq[j][ 7] = e1.w;
        gq[j][ 8] = e2.x; gq[j][ 9] = e2.y; gq[j][10] = e2.z; gq[j][11] = e2.w;
        gq[j][12] = e3.x; gq[j][13] = e3.y; gq[j][14] = e3.z; gq[j][15] = e3.w;
    }
    float* ob = oblk + 4 * quad;
    #pragma unroll
    for (int c = 0; c < 16; ++c) {
        float4 v = make_float4(gq[0][c], gq[1][c], gq[2][c], gq[3][c]);
        *(float4*)(ob + (size_t)(16 * cgrp + c) * HWSZ) = v;   // 1KB/channel/wave
    }

    // ---- block loss reduction + fused last-block finalization ----
    #pragma unroll
    for (int off = 32; off; off >>= 1) lsum += __shfl_down(lsum, off, 64);
    if (lane == 0) sRed[w] = lsum;
    __syncthreads();
    if (tid == 0) {
        float total = (sRed[0] + sRed[1]) + (sRed[2] + sRed[3]);
        __hip_atomic_store(&partial[blockIdx.x], total,
                           __ATOMIC_RELEASE, __HIP_MEMORY_SCOPE_AGENT);
        unsigned prev = __hip_atomic_fetch_add(counter, 1u,
                           __ATOMIC_ACQ_REL, __HIP_MEMORY_SCOPE_AGENT);
        sLast = (prev == NBLK - 1) ? 1 : 0;   // counter memset to 0 each launch
    }
    __syncthreads();
    if (sLast) {                            // exactly one block runs this
        float v = __hip_atomic_load(&partial[tid], __ATOMIC_RELAXED,
                                    __HIP_MEMORY_SCOPE_AGENT) +
                  __hip_atomic_load(&partial[tid + 256], __ATOMIC_RELAXED,
                                    __HIP_MEMORY_SCOPE_AGENT);
        #pragma unroll
        for (int off = 32; off; off >>= 1) v += __shfl_down(v, off, 64);
        if (lane == 0) sRed[w] = v;
        __syncthreads();
        if (tid == 0)
            out[(size_t)NROWS * DD] =
                ((sRed[0] + sRed[1]) + (sRed[2] + sRed[3])) * (1.25f / 8388608.0f);
    }
}

extern "C" void kernel_launch(void* const* d_in, const int* in_sizes, int n_in,
                              void* d_out, int out_size, void* d_ws, size_t ws_size,
                              hipStream_t stream) {
    const float* x   = (const float*)d_in[0];   // [32,64,64,64] NCHW
    const float* emb = (const float*)d_in[1];   // [512,64]
    float* out        = (float*)d_out;
    unsigned* counter = (unsigned*)d_ws;        // zeroed every launch below
    float* partial    = (float*)((char*)d_ws + 256);   // NBLK floats

    hipMemsetAsync(d_ws, 0, 256, stream);       // graph-capture-safe (R8-proven)
    vq_mfma<<<NBLK, 256, 0, stream>>>(x, emb, out, counter, partial);
}

// Round 15
// 37.088 us; speedup vs baseline: 2.4825x; 1.6873x over previous
//
#include <hip/hip_runtime.h>

// VQ-VAE quantization via fused bf16-MFMA argmin. 1024 blocks x 128 rows
// (VGPR<=128 + 21KB LDS -> 4 blocks/CU resident), whole tile staged at once,
// ONE barrier before compute, one before epilogue, separate tiny loss kernel
// (NO device-scope atomics - R14 proved they cost +31us in L2 flushes).
// B=32, D=64, HW=4096, K=512.
// out[0..8388608)=quantized NCHW, out[8388608]=loss=1.25*mean((q-x)^2).
#define KK    512
#define DD    64
#define HWSZ  4096
#define NROWS 131072
#define RPB   128                  // rows per block
#define NSUB  4                    // 32-row sub-tiles per block
#define NBLK  (NROWS / RPB)        // 1024

typedef short short8 __attribute__((ext_vector_type(8)));
typedef float f32x16 __attribute__((ext_vector_type(16)));

static __device__ __forceinline__ unsigned cvtpk(float lo, float hi) {
    unsigned r;                    // r = bf16(lo) | bf16(hi)<<16, RNE
    asm("v_cvt_pk_bf16_f32 %0, %1, %2" : "=v"(r) : "v"(lo), "v"(hi));
    return r;
}
static __device__ __forceinline__ float    u2f(unsigned u) { return __builtin_bit_cast(float, u); }
static __device__ __forceinline__ unsigned f2u(float f)    { return __builtin_bit_cast(unsigned, f); }
static __device__ __forceinline__ float mx3(float a, float b, float c) {
    return fmaxf(fmaxf(a, b), c);  // clang fuses to v_max3_f32
}

// lgkm-only barrier: global loads stay in flight (no vmcnt drain)
#define LGKM0_BAR() do { asm volatile("s_waitcnt lgkmcnt(0)" ::: "memory"); \
                         __builtin_amdgcn_s_barrier();                      \
                         asm volatile("" ::: "memory"); } while (0)

__global__ __launch_bounds__(256, 2) void vq_mfma(
    const float* __restrict__ x, const float* __restrict__ emb,
    float* __restrict__ out, float* __restrict__ partial)
{
    __shared__ float    sH[KK];             // -0.5*||e_k||^2 (wave-private slices)
    __shared__ unsigned sX[NSUB][32 * 32];  // 16 KB: whole 128-row tile, packed bf16
    __shared__ float    sKey[NSUB][4][32];  // [subtile][wave][row] packed keys
    __shared__ float    sRed[4];

    const int tid  = threadIdx.x;
    const int lane = tid & 63;
    const int w    = tid >> 6;              // wave owns codes [w*128, w*128+128)
    const int g    = lane >> 5;
    const int wbase = w * 128;

    const int base = blockIdx.x * RPB;      // 128 consecutive hw rows, b constant
    const int b    = base >> 12;
    const int hwb  = base & 4095;
    const float* xblk = x   + (size_t)b * (DD * HWSZ) + hwb;
    float*       oblk = out + (size_t)b * (DD * HWSZ) + hwb;

    const int cp  = tid >> 3;               // staging: channel pair 0..31
    const int hwq = (tid & 7) * 4;          // staging: hw quad

    // ---- issue ALL x loads up front; latency hidden under A-frag setup ----
    float4 xa[NSUB], xbv[NSUB];
    #pragma unroll
    for (int s = 0; s < NSUB; ++s) {
        const float* xs = xblk + 32 * s;
        xa[s]  = *(const float4*)(xs + (size_t)(2*cp)   * HWSZ + hwq);
        xbv[s] = *(const float4*)(xs + (size_t)(2*cp+1) * HWSZ + hwq);
    }

    // ---- persistent codebook A-fragments; -e^2/2 (wave-private, no barrier) ----
    short8 afrag[4][4];
    #pragma unroll
    for (int ct = 0; ct < 4; ++ct) {
        const int code = wbase + ct * 32 + (lane & 31);
        float e2h = 0.f;
        #pragma unroll
        for (int m = 0; m < 4; ++m) {
            const float* ep = emb + code * DD + m * 16 + 8 * g;
            float4 a  = *(const float4*)ep;
            float4 b4 = *(const float4*)(ep + 4);
            union { unsigned u[4]; short8 s; } cv;
            cv.u[0] = cvtpk(a.x, a.y);   cv.u[1] = cvtpk(a.z, a.w);
            cv.u[2] = cvtpk(b4.x, b4.y); cv.u[3] = cvtpk(b4.z, b4.w);
            afrag[ct][m] = cv.s;
            e2h = fmaf(a.x,a.x,e2h);   e2h = fmaf(a.y,a.y,e2h);
            e2h = fmaf(a.z,a.z,e2h);   e2h = fmaf(a.w,a.w,e2h);
            e2h = fmaf(b4.x,b4.x,e2h); e2h = fmaf(b4.y,b4.y,e2h);
            e2h = fmaf(b4.z,b4.z,e2h); e2h = fmaf(b4.w,b4.w,e2h);
        }
        float e2f = e2h + __shfl_xor(e2h, 32, 64);
        if (lane < 32) sH[code] = -0.5f * e2f;
    }

    // ---- pack whole tile -> sX; thread-local fp32 sum(x^2) ----
    float xsq = 0.f;
    #pragma unroll
    for (int s = 0; s < NSUB; ++s) {
        float4 fa = xa[s], fb = xbv[s];
        uint4 dw = { cvtpk(fa.x, fb.x), cvtpk(fa.y, fb.y),
                     cvtpk(fa.z, fb.z), cvtpk(fa.w, fb.w) };
        *(uint4*)&sX[s][cp * 32 + hwq] = dw;
        xsq = fmaf(fa.x,fa.x,xsq); xsq = fmaf(fa.y,fa.y,xsq);
        xsq = fmaf(fa.z,fa.z,xsq); xsq = fmaf(fa.w,fa.w,xsq);
        xsq = fmaf(fb.x,fb.x,xsq); xsq = fmaf(fb.y,fb.y,xsq);
        xsq = fmaf(fb.z,fb.z,xsq); xsq = fmaf(fb.w,fb.w,xsq);
    }

    // ---- hoist acc-init to registers (wave-own sH slice, read once) ----
    float4 e2r[4][4];
    #pragma unroll
    for (int ct = 0; ct < 4; ++ct)
        #pragma unroll
        for (int i = 0; i < 4; ++i)
            e2r[ct][i] = *(const float4*)(sH + wbase + ct * 32 + 4 * g + 8 * i);

    LGKM0_BAR();                            // #1: all sX staged (sH wave-private)

    const unsigned cbase = (unsigned)(wbase + 4 * g);

    // ---- 4 sub-tiles back-to-back, ZERO barriers between ----
    #pragma unroll 1
    for (int s = 0; s < NSUB; ++s) {
        short8 bfrag[4];
        #pragma unroll
        for (int m = 0; m < 4; ++m) {
            const unsigned* sp = &sX[s][(m * 8 + 4 * g) * 32 + (lane & 31)];
            union { unsigned u[4]; short8 s8; } cv;
            cv.u[0] = sp[0]; cv.u[1] = sp[32]; cv.u[2] = sp[64]; cv.u[3] = sp[96];
            bfrag[m] = cv.s8;
        }
        float kwave;
        #pragma unroll
        for (int ct = 0; ct < 4; ++ct) {
            f32x16 acc;
            #pragma unroll
            for (int i = 0; i < 4; ++i) {
                acc[4*i]   = e2r[ct][i].x; acc[4*i+1] = e2r[ct][i].y;
                acc[4*i+2] = e2r[ct][i].z; acc[4*i+3] = e2r[ct][i].w;
            }
            #pragma unroll
            for (int m = 0; m < 4; ++m)
                acc = __builtin_amdgcn_mfma_f32_32x32x16_bf16(afrag[ct][m], bfrag[m], acc, 0, 0, 0);
            float k[16];
            #pragma unroll
            for (int r = 0; r < 16; ++r)
                k[r] = u2f((f2u(acc[r]) & 0xFFFFFE00u) |
                           (cbase + (unsigned)(ct * 32 + (r & 3) + 8 * (r >> 2))));
            float t0 = mx3(k[0],  k[1],  k[2]);
            float t1 = mx3(k[3],  k[4],  k[5]);
            float t2 = mx3(k[6],  k[7],  k[8]);
            float t3 = mx3(k[9],  k[10], k[11]);
            float t4 = mx3(k[12], k[13], k[14]);
            float kct = mx3(mx3(t0, t1, k[15]), fmaxf(t2, t3), t4);
            kwave = ct ? fmaxf(kwave, kct) : kct;
        }
        float k2 = fmaxf(kwave, __shfl_xor(kwave, 32, 64));
        if (lane < 32) sKey[s][w][lane] = k2;
    }

    LGKM0_BAR();                            // #2: all sKey slices ready

    // ---- epilogue: thread = (row-quad 0..31, 8-channel group 0..7) ----
    const int quad = tid & 31;              // rows 4*quad .. 4*quad+3
    const int cgrp = tid >> 5;              // channels 8*cgrp .. 8*cgrp+7
    const int s    = quad >> 3;             // sub-tile of this quad
    float lsum = xsq;                       // loss: sum x^2 - 2*sum(best score)
    float gq[4][8];
    #pragma unroll
    for (int j = 0; j < 4; ++j) {
        const int r32 = (quad & 7) * 4 + j;
        float kf = fmaxf(fmaxf(sKey[s][0][r32], sKey[s][1][r32]),
                         fmaxf(sKey[s][2][r32], sKey[s][3][r32]));
        const int code = (int)(f2u(kf) & 511u);
        if (cgrp == 0)
            lsum = fmaf(-2.f, u2f(f2u(kf) & 0xFFFFFE00u), lsum);
        const float* eq = emb + code * DD + 8 * cgrp;
        float4 e0 = *(const float4*)eq;
        float4 e1 = *(const float4*)(eq + 4);
        gq[j][0] = e0.x; gq[j][1] = e0.y; gq[j][2] = e0.z; gq[j][3] = e0.w;
        gq[j][4] = e1.x; gq[j][5] = e1.y; gq[j][6] = e1.z; gq[j][7] = e1.w;
    }
    float* ob = oblk + 4 * quad;
    #pragma unroll
    for (int c = 0; c < 8; ++c) {
        float4 v = make_float4(gq[0][c], gq[1][c], gq[2][c], gq[3][c]);
        *(float4*)(ob + (size_t)(8 * cgrp + c) * HWSZ) = v;   // 512B/half-wave
    }

    // ---- deterministic block loss reduction (plain store, NO atomics) ----
    #pragma unroll
    for (int off = 32; off; off >>= 1) lsum += __shfl_down(lsum, off, 64);
    if (lane == 0) sRed[w] = lsum;
    __syncthreads();
    if (tid == 0) partial[blockIdx.x] = (sRed[0] + sRed[1]) + (sRed[2] + sRed[3]);
}

__global__ __launch_bounds__(256) void vq_loss(
    const float* __restrict__ partial, float* __restrict__ loss)
{
    __shared__ float sRed[4];
    float v = 0.f;
    #pragma unroll
    for (int i = 0; i < NBLK / 256; ++i) v += partial[threadIdx.x + i * 256];
    #pragma unroll
    for (int off = 32; off; off >>= 1) v += __shfl_down(v, off, 64);
    if ((threadIdx.x & 63) == 0) sRed[threadIdx.x >> 6] = v;
    __syncthreads();
    if (threadIdx.x == 0)
        loss[0] = ((sRed[0] + sRed[1]) + (sRed[2] + sRed[3])) * (1.25f / 8388608.0f);
}

extern "C" void kernel_launch(void* const* d_in, const int* in_sizes, int n_in,
                              void* d_out, int out_size, void* d_ws, size_t ws_size,
                              hipStream_t stream) {
    const float* x   = (const float*)d_in[0];   // [32,64,64,64] NCHW
    const float* emb = (const float*)d_in[1];   // [512,64]
    float* out     = (float*)d_out;
    float* partial = (float*)d_ws;              // NBLK floats

    vq_mfma<<<NBLK, 256, 0, stream>>>(x, emb, out, partial);
    vq_loss<<<1, 256, 0, stream>>>(partial, out + (size_t)NROWS * DD);
}